// Round 10
// baseline (17.929 us; speedup 1.0000x reference)
//
#include <hip/hip_runtime.h>
#include <hip/hip_bf16.h>

#define N_DIMS 128
#define BLOCK 256
#define SIG_STRIDE 16   // u64s per signal line = 128 bytes
#define SIG_MAGIC 0x5A17C0DE9E2F5D81ULL

// Single-dispatch producer-consumer fusion, v7: all-blocks-produce +
// pre-barrier index prefetch.
//
// Proven mechanics kept from R9 (15.9us):
//   - table publish: relaxed agent-scope (sc1 write-through) stores ->
//     s_waitcnt vmcnt(0) -> __syncthreads -> ONE plain magic store per block
//     on a private 128B line (no RMW, no line sharing).
//   - barrier: thread t polls sig[t], sig[t+256]; LDS-reduced; poison-proof
//     (0xAA.. != magic).
//   - gather reads the table with normal CACHED loads only AFTER the
//     barrier (L2 has no stale copy: launch acquire invalidated it, and the
//     producer stores are write-through/no-allocate).
// New in v7:
//   - producer work spread over ALL blocks: 8-lane group g of global wave w
//     computes node w + g*total_waves (round-robin) -> producer critical
//     path drops from 32 to ~21 nodes/block and no block idles.
//   - edge-index uint4 loads are ISSUED BEFORE the producer phase and
//     consumed after the barrier: the 8MB index fetch (largest HBM read)
//     overlaps production+poll. The producer's vmcnt(0) retires them into
//     VGPRs, which is harmless.
//
// Deadlock-free: no block waits on a block that waits back; 489 blocks
// (1956 waves, VGPR<=96) co-resident on 256 CUs regardless of order.

__device__ __forceinline__ unsigned int bf16_rne(float f) {
  union { float f; unsigned int u; } x; x.f = f;
  return (x.u + 0x7fffu + ((x.u >> 16) & 1u)) >> 16;
}

__device__ __forceinline__ unsigned long long pack3(float a, float b, float c) {
  return (unsigned long long)bf16_rne(a) |
         ((unsigned long long)bf16_rne(b) << 16) |
         ((unsigned long long)bf16_rne(c) << 32);
}

__device__ __forceinline__ float unpack3(unsigned long long v, int c) {
  union { unsigned int u; float f; } x;
  x.u = ((unsigned int)(v >> (16 * c)) & 0xffffu) << 16;
  return x.f;
}

__global__ __launch_bounds__(BLOCK) void hetero_fused_v7(
    const float* __restrict__ h, const float* __restrict__ W,
    const float* __restrict__ b, const unsigned int* __restrict__ src32,
    const unsigned int* __restrict__ dst32,
    unsigned long long* __restrict__ tbl,   // [2*n_nodes]: 2n=src, 2n+1=dst
    unsigned long long* __restrict__ sig,   // [gridDim.x * SIG_STRIDE]
    float* __restrict__ out, int n_nodes, int n_edges) {
  __shared__ int s_nz;
  __shared__ int s_wait;
  if (threadIdx.x == 0) s_nz = 0;
  __syncthreads();
  {
    int i = threadIdx.x;
    if (2 * i + 1 < n_edges) {
      if (src32[2 * i + 1] != 0u) s_nz = 1;  // benign race
    }
  }
  __syncthreads();
  const int shift = s_nz ? 0 : 1;            // 1 => int64 layout

  // ---- Pre-barrier index prefetch (inputs, never stale) ----
  const int gtid = blockIdx.x * BLOCK + threadIdx.x;
  const int e0   = gtid * 4;
  const bool main_path = (e0 + 3 < n_edges);
  uint4 pa, pb, pc, pd;   // raw index words, decoded after the barrier
  if (main_path) {
    const uint4* sp = (const uint4*)(src32 + ((size_t)e0 << shift));
    const uint4* dp = (const uint4*)(dst32 + ((size_t)e0 << shift));
    pa = sp[0];
    pc = dp[0];
    if (shift) { pb = sp[1]; pd = dp[1]; }
  }

  // ---- Producer phase: every block, round-robin nodes ----
  {
    const float4* h4 = (const float4*)h;
    const float4* W4 = (const float4*)W;     // W row = 256 floats = 64 float4
    const int wtot = gridDim.x * (BLOCK / 64);
    int w    = (blockIdx.x * BLOCK + threadIdx.x) >> 6;
    int lane = threadIdx.x & 63;
    int g    = lane >> 3;     // 8 node-groups per wave
    int sub  = lane & 7;      // 8 lanes per node, 16 dims each
    int node = w + g * wtot;  // round-robin: block load ~= n_nodes/grid
    if (node < n_nodes) {
      float acc[6] = {0.f, 0.f, 0.f, 0.f, 0.f, 0.f};
#pragma unroll
      for (int k = 0; k < 4; ++k) {
        float4 hv = h4[(size_t)node * 32 + sub * 4 + k];
#pragma unroll
        for (int c = 0; c < 3; ++c) {
          float4 ws = W4[c * 64 + sub * 4 + k];
          float4 wd = W4[c * 64 + 32 + sub * 4 + k];
          acc[c]     += hv.x * ws.x + hv.y * ws.y + hv.z * ws.z + hv.w * ws.w;
          acc[3 + c] += hv.x * wd.x + hv.y * wd.y + hv.z * wd.z + hv.w * wd.w;
        }
      }
#pragma unroll
      for (int off = 1; off <= 4; off <<= 1) {
#pragma unroll
        for (int k = 0; k < 6; ++k) acc[k] += __shfl_xor(acc[k], off, 64);
      }
      if (sub == 0) {
        __hip_atomic_store(&tbl[2 * node], pack3(acc[0], acc[1], acc[2]),
                           __ATOMIC_RELAXED, __HIP_MEMORY_SCOPE_AGENT);
        __hip_atomic_store(&tbl[2 * node + 1],
                           pack3(acc[3] + b[0], acc[4] + b[1], acc[5] + b[2]),
                           __ATOMIC_RELAXED, __HIP_MEMORY_SCOPE_AGENT);
      }
    }
    // Drain table stores (also retires the index prefetch into VGPRs),
    // then one plain signal store per block on its private line.
    asm volatile("s_waitcnt vmcnt(0)" ::: "memory");
    __syncthreads();
    if (threadIdx.x == 0)
      __hip_atomic_store(&sig[(size_t)blockIdx.x * SIG_STRIDE], SIG_MAGIC,
                         __ATOMIC_RELAXED, __HIP_MEMORY_SCOPE_AGENT);
  }

  // ---- Barrier: distributed poll over gridDim.x signals ----
  {
    const int nsig = gridDim.x;
    int t1 = threadIdx.x;
    int t2 = threadIdx.x + BLOCK;
    for (;;) {
      if (threadIdx.x == 0) s_wait = 0;
      __syncthreads();
      int bad = 0;
      if (t1 < nsig)
        bad |= (__hip_atomic_load(&sig[(size_t)t1 * SIG_STRIDE],
                                  __ATOMIC_RELAXED,
                                  __HIP_MEMORY_SCOPE_AGENT) != SIG_MAGIC);
      if (t2 < nsig)
        bad |= (__hip_atomic_load(&sig[(size_t)t2 * SIG_STRIDE],
                                  __ATOMIC_RELAXED,
                                  __HIP_MEMORY_SCOPE_AGENT) != SIG_MAGIC);
      if (bad) s_wait = 1;  // benign race
      __syncthreads();
      if (!s_wait) break;
      __builtin_amdgcn_s_sleep(2);
    }
  }
  asm volatile("" ::: "memory");  // keep table loads below the barrier

  // ---- Consumer phase: decode prefetched indices, cached table gather ----
  if (main_path) {
    unsigned s[4], d[4];
    if (shift) {  // int64: even words of the two uint4s
      s[0] = pa.x; s[1] = pa.z; s[2] = pb.x; s[3] = pb.z;
      d[0] = pc.x; d[1] = pc.z; d[2] = pd.x; d[3] = pd.z;
    } else {      // int32
      s[0] = pa.x; s[1] = pa.y; s[2] = pa.z; s[3] = pa.w;
      d[0] = pc.x; d[1] = pc.y; d[2] = pc.z; d[3] = pc.w;
    }
    unsigned long long es[4], ed[4];
#pragma unroll
    for (int k = 0; k < 4; ++k) {   // 8 independent cached loads for ILP
      es[k] = tbl[2 * s[k]];
      ed[k] = tbl[2 * d[k] + 1];
    }
    float r[12];
#pragma unroll
    for (int k = 0; k < 4; ++k) {
      r[k * 3 + 0] = unpack3(es[k], 0) + unpack3(ed[k], 0);
      r[k * 3 + 1] = unpack3(es[k], 1) + unpack3(ed[k], 1);
      r[k * 3 + 2] = unpack3(es[k], 2) + unpack3(ed[k], 2);
    }
    float4* o4 = (float4*)(out + (size_t)e0 * 3);  // e0*12B, 16B aligned
    o4[0] = make_float4(r[0], r[1], r[2],  r[3]);
    o4[1] = make_float4(r[4], r[5], r[6],  r[7]);
    o4[2] = make_float4(r[8], r[9], r[10], r[11]);
  } else if (e0 < n_edges) {
    for (int e = e0; e < n_edges; ++e) {
      unsigned s = src32[(size_t)e << shift];
      unsigned d = dst32[(size_t)e << shift];
      unsigned long long es = tbl[2 * s];
      unsigned long long ed = tbl[2 * d + 1];
      out[(size_t)e * 3 + 0] = unpack3(es, 0) + unpack3(ed, 0);
      out[(size_t)e * 3 + 1] = unpack3(es, 1) + unpack3(ed, 1);
      out[(size_t)e * 3 + 2] = unpack3(es, 2) + unpack3(ed, 2);
    }
  }
}

extern "C" void kernel_launch(void* const* d_in, const int* in_sizes, int n_in,
                              void* d_out, int out_size, void* d_ws, size_t ws_size,
                              hipStream_t stream) {
  const float*        h     = (const float*)d_in[0];
  const unsigned int* src32 = (const unsigned int*)d_in[1];
  const unsigned int* dst32 = (const unsigned int*)d_in[2];
  const float*        W     = (const float*)d_in[3];
  const float*        b     = (const float*)d_in[4];
  float*              out   = (float*)d_out;

  int n_nodes = in_sizes[0] / N_DIMS;  // 10000
  int n_edges = in_sizes[1];           // 500000

  char* ws = (char*)d_ws;
  unsigned long long* tbl = (unsigned long long*)ws;            // 160 KB
  size_t sig_off = ((2 * (size_t)n_nodes * 8) + 4095) & ~4095ull;
  unsigned long long* sig = (unsigned long long*)(ws + sig_off); // 489*128B

  int gather_blocks = (n_edges / 4 + BLOCK - 1) / BLOCK;   // 489
  int node_blocks   = (n_nodes + 31) / 32;                 // 313
  int grid = gather_blocks > node_blocks ? gather_blocks : node_blocks;
  // grid = 489 <= 512 (poll covers 2*BLOCK signals)

  hetero_fused_v7<<<grid, BLOCK, 0, stream>>>(
      h, W, b, src32, dst32, tbl, sig, out, n_nodes, n_edges);
}

// Round 11
// 16.176 us; speedup vs baseline: 1.1084x; 1.1084x over previous
//
#include <hip/hip_runtime.h>
#include <hip/hip_bf16.h>

#define N_DIMS 128
#define BLOCK 256
#define SIG_STRIDE 16   // u64s per signal line = 128 bytes
#define SIG_MAGIC 0x5A17C0DE9E2F5D81ULL

// Single-dispatch producer-consumer fusion, v8 = R9 structure + safely-placed
// index prefetch.
//
// R10 post-mortem (v7 regressed 15.9 -> 17.9):
//   - round-robin node production broke wave-level coalescing of the h read
//     (8 scattered 512B bursts vs one contiguous 4KB burst per wave) and
//     grew the barrier from 313 to 489 signals. REVERTED: producer blocks
//     0..312 own 32 CONSECUTIVE nodes; a wave reads 8 consecutive h-rows.
//   - index prefetch before the producer's vmcnt(0) delayed every signal by
//     that block's index fetch. MOVED: prefetch issues AFTER the signal
//     store (producers) / immediately (pure consumers), so the ~8MB index
//     fetch overlaps the barrier poll and delays nothing.
//
// Proven mechanics kept from R9 (15.9us):
//   - table publish: relaxed agent-scope (write-through) stores ->
//     s_waitcnt vmcnt(0) -> __syncthreads -> ONE plain magic store per
//     producer block on a private 128B line (no RMW, no line sharing).
//   - barrier: thread t polls sig[t] / sig[t+256] with plain uncached
//     loads, LDS-reduced; poison-proof (0xAA.. != magic).
//   - gather reads the table with normal CACHED loads only AFTER the
//     barrier (no stale L2 copy: launch acquire invalidated, producer
//     stores are write-through/no-allocate).
//
// Deadlock-free: producers never wait; 489 blocks (1956 waves) co-resident
// on 256 CUs regardless of dispatch order.

__device__ __forceinline__ unsigned int bf16_rne(float f) {
  union { float f; unsigned int u; } x; x.f = f;
  return (x.u + 0x7fffu + ((x.u >> 16) & 1u)) >> 16;
}

__device__ __forceinline__ unsigned long long pack3(float a, float b, float c) {
  return (unsigned long long)bf16_rne(a) |
         ((unsigned long long)bf16_rne(b) << 16) |
         ((unsigned long long)bf16_rne(c) << 32);
}

__device__ __forceinline__ float unpack3(unsigned long long v, int c) {
  union { unsigned int u; float f; } x;
  x.u = ((unsigned int)(v >> (16 * c)) & 0xffffu) << 16;
  return x.f;
}

__global__ __launch_bounds__(BLOCK) void hetero_fused_v8(
    const float* __restrict__ h, const float* __restrict__ W,
    const float* __restrict__ b, const unsigned int* __restrict__ src32,
    const unsigned int* __restrict__ dst32,
    unsigned long long* __restrict__ tbl,   // [2*n_nodes]: 2n=src, 2n+1=dst
    unsigned long long* __restrict__ sig,   // [prod_blocks * SIG_STRIDE]
    float* __restrict__ out, int n_nodes, int n_edges, int prod_blocks) {
  // ---- Per-block index-width self-detection ----
  __shared__ int s_nz;
  __shared__ int s_wait;
  if (threadIdx.x == 0) s_nz = 0;
  __syncthreads();
  {
    int i = threadIdx.x;
    if (2 * i + 1 < n_edges) {
      if (src32[2 * i + 1] != 0u) s_nz = 1;  // benign race
    }
  }
  __syncthreads();
  const int shift = s_nz ? 0 : 1;            // 1 => int64 layout

  // ---- Producer phase: blocks 0..prod_blocks-1, 32 CONSECUTIVE nodes ----
  if ((int)blockIdx.x < prod_blocks) {
    const float4* h4 = (const float4*)h;
    const float4* W4 = (const float4*)W;     // W row = 256 floats = 64 float4
    int wave = (blockIdx.x * BLOCK + threadIdx.x) >> 6;
    int lane = threadIdx.x & 63;
    int g    = lane >> 3;     // 8 nodes per wave (consecutive -> coalesced)
    int sub  = lane & 7;      // 8 lanes per node, 16 dims each
    int node = wave * 8 + g;
    if (node < n_nodes) {
      float acc[6] = {0.f, 0.f, 0.f, 0.f, 0.f, 0.f};
#pragma unroll
      for (int k = 0; k < 4; ++k) {
        float4 hv = h4[(size_t)node * 32 + sub * 4 + k];
#pragma unroll
        for (int c = 0; c < 3; ++c) {
          float4 ws = W4[c * 64 + sub * 4 + k];
          float4 wd = W4[c * 64 + 32 + sub * 4 + k];
          acc[c]     += hv.x * ws.x + hv.y * ws.y + hv.z * ws.z + hv.w * ws.w;
          acc[3 + c] += hv.x * wd.x + hv.y * wd.y + hv.z * wd.z + hv.w * wd.w;
        }
      }
#pragma unroll
      for (int off = 1; off <= 4; off <<= 1) {
#pragma unroll
        for (int k = 0; k < 6; ++k) acc[k] += __shfl_xor(acc[k], off, 64);
      }
      if (sub == 0) {
        __hip_atomic_store(&tbl[2 * node], pack3(acc[0], acc[1], acc[2]),
                           __ATOMIC_RELAXED, __HIP_MEMORY_SCOPE_AGENT);
        __hip_atomic_store(&tbl[2 * node + 1],
                           pack3(acc[3] + b[0], acc[4] + b[1], acc[5] + b[2]),
                           __ATOMIC_RELAXED, __HIP_MEMORY_SCOPE_AGENT);
      }
    }
    // Drain this wave's table stores to the coherent point, then one plain
    // signal store per block on its private 128B line.
    asm volatile("s_waitcnt vmcnt(0)" ::: "memory");
    __syncthreads();
    if (threadIdx.x == 0)
      __hip_atomic_store(&sig[(size_t)blockIdx.x * SIG_STRIDE], SIG_MAGIC,
                         __ATOMIC_RELAXED, __HIP_MEMORY_SCOPE_AGENT);
  }

  // ---- Index prefetch: AFTER the signal store, BEFORE the poll ----
  // Cannot delay any signal; the ~8MB index fetch overlaps the barrier.
  const int gtid = blockIdx.x * BLOCK + threadIdx.x;
  const int e0   = gtid * 4;
  const bool main_path = (e0 + 3 < n_edges);
  uint4 pa, pb, pc, pd;   // raw index words, decoded after the barrier
  if (main_path) {
    const uint4* sp = (const uint4*)(src32 + ((size_t)e0 << shift));
    const uint4* dp = (const uint4*)(dst32 + ((size_t)e0 << shift));
    pa = sp[0];
    pc = dp[0];
    if (shift) { pb = sp[1]; pd = dp[1]; }
  }

  // ---- Barrier: distributed poll, one signal per thread (plain loads) ----
  {
    int t1 = threadIdx.x;
    int t2 = threadIdx.x + BLOCK;
    for (;;) {
      if (threadIdx.x == 0) s_wait = 0;
      __syncthreads();
      int bad = 0;
      if (t1 < prod_blocks)
        bad |= (__hip_atomic_load(&sig[(size_t)t1 * SIG_STRIDE],
                                  __ATOMIC_RELAXED,
                                  __HIP_MEMORY_SCOPE_AGENT) != SIG_MAGIC);
      if (t2 < prod_blocks)
        bad |= (__hip_atomic_load(&sig[(size_t)t2 * SIG_STRIDE],
                                  __ATOMIC_RELAXED,
                                  __HIP_MEMORY_SCOPE_AGENT) != SIG_MAGIC);
      if (bad) s_wait = 1;  // benign race
      __syncthreads();
      if (!s_wait) break;
      __builtin_amdgcn_s_sleep(2);
    }
  }
  asm volatile("" ::: "memory");  // keep table loads below the barrier

  // ---- Consumer phase: decode prefetched indices, cached table gather ----
  if (main_path) {
    unsigned s[4], d[4];
    if (shift) {  // int64: even words of the two uint4s
      s[0] = pa.x; s[1] = pa.z; s[2] = pb.x; s[3] = pb.z;
      d[0] = pc.x; d[1] = pc.z; d[2] = pd.x; d[3] = pd.z;
    } else {      // int32
      s[0] = pa.x; s[1] = pa.y; s[2] = pa.z; s[3] = pa.w;
      d[0] = pc.x; d[1] = pc.y; d[2] = pc.z; d[3] = pc.w;
    }
    unsigned long long es[4], ed[4];
#pragma unroll
    for (int k = 0; k < 4; ++k) {   // 8 independent cached loads for ILP
      es[k] = tbl[2 * s[k]];
      ed[k] = tbl[2 * d[k] + 1];
    }
    float r[12];
#pragma unroll
    for (int k = 0; k < 4; ++k) {
      r[k * 3 + 0] = unpack3(es[k], 0) + unpack3(ed[k], 0);
      r[k * 3 + 1] = unpack3(es[k], 1) + unpack3(ed[k], 1);
      r[k * 3 + 2] = unpack3(es[k], 2) + unpack3(ed[k], 2);
    }
    float4* o4 = (float4*)(out + (size_t)e0 * 3);  // e0*12B, 16B aligned
    o4[0] = make_float4(r[0], r[1], r[2],  r[3]);
    o4[1] = make_float4(r[4], r[5], r[6],  r[7]);
    o4[2] = make_float4(r[8], r[9], r[10], r[11]);
  } else if (e0 < n_edges) {
    for (int e = e0; e < n_edges; ++e) {
      unsigned s = src32[(size_t)e << shift];
      unsigned d = dst32[(size_t)e << shift];
      unsigned long long es = tbl[2 * s];
      unsigned long long ed = tbl[2 * d + 1];
      out[(size_t)e * 3 + 0] = unpack3(es, 0) + unpack3(ed, 0);
      out[(size_t)e * 3 + 1] = unpack3(es, 1) + unpack3(ed, 1);
      out[(size_t)e * 3 + 2] = unpack3(es, 2) + unpack3(ed, 2);
    }
  }
}

extern "C" void kernel_launch(void* const* d_in, const int* in_sizes, int n_in,
                              void* d_out, int out_size, void* d_ws, size_t ws_size,
                              hipStream_t stream) {
  const float*        h     = (const float*)d_in[0];
  const unsigned int* src32 = (const unsigned int*)d_in[1];
  const unsigned int* dst32 = (const unsigned int*)d_in[2];
  const float*        W     = (const float*)d_in[3];
  const float*        b     = (const float*)d_in[4];
  float*              out   = (float*)d_out;

  int n_nodes = in_sizes[0] / N_DIMS;  // 10000
  int n_edges = in_sizes[1];           // 500000

  char* ws = (char*)d_ws;
  unsigned long long* tbl = (unsigned long long*)ws;            // 160 KB
  size_t sig_off = ((2 * (size_t)n_nodes * 8) + 4095) & ~4095ull;
  unsigned long long* sig = (unsigned long long*)(ws + sig_off); // 313*128B

  int prod_blocks   = (n_nodes + 31) / 32;                 // 313 (<= 512)
  int gather_blocks = (n_edges / 4 + BLOCK - 1) / BLOCK;   // 489
  int grid = gather_blocks > prod_blocks ? gather_blocks : prod_blocks;

  hetero_fused_v8<<<grid, BLOCK, 0, stream>>>(
      h, W, b, src32, dst32, tbl, sig, out, n_nodes, n_edges, prod_blocks);
}